// Round 11
// baseline (792.064 us; speedup 1.0000x reference)
//
#include <hip/hip_runtime.h>
#include <cstddef>

typedef __attribute__((ext_vector_type(8))) short short8;
typedef __attribute__((ext_vector_type(4))) float floatx4;

// ---------------------------------------------------------------- bf16 utils
__device__ __forceinline__ unsigned short f2bf(float f) {
  union { float f; unsigned u; } v; v.f = f;
  const unsigned r = v.u + 0x7fffu + ((v.u >> 16) & 1u);  // RNE
  return (unsigned short)(r >> 16);
}

// ---------------------------------------------------------------- reductions
__device__ __forceinline__ float block_reduce_sum(float v, float* sm) {
#pragma unroll
  for (int off = 32; off > 0; off >>= 1) v += __shfl_down(v, off, 64);
  const int lane = threadIdx.x & 63, wid = threadIdx.x >> 6;
  __syncthreads();
  if (lane == 0) sm[wid] = v;
  __syncthreads();
  if (threadIdx.x == 0) {
    float t = 0.f;
    const int nw = (blockDim.x + 63) >> 6;
    for (int i = 0; i < nw; ++i) t += sm[i];
    sm[0] = t;
  }
  __syncthreads();
  return sm[0];
}

// ---------------------------------------------------------------- ternarize
// red[t*4+0]=sum|w|, red[t*4+1]=masked count, red[t*4+2]=masked sum|w|.
__device__ __forceinline__ void tsel(int t, const float* w0, const float* w1,
                                     const float* w2, const float* w3, int n0,
                                     int n1, int n2, int n3,
                                     const float*& w, int& n) {
  w = (t == 0) ? w0 : (t == 1) ? w1 : (t == 2) ? w2 : w3;
  n = (t == 0) ? n0 : (t == 1) ? n1 : (t == 2) ? n2 : n3;
}

__global__ __launch_bounds__(256) void tern_phase1(
    const float* w0, const float* w1, const float* w2, const float* w3,
    int n0, int n1, int n2, int n3, float* __restrict__ red) {
  __shared__ float sm[8];
  const float* w; int n;
  tsel(blockIdx.y, w0, w1, w2, w3, n0, n1, n2, n3, w, n);
  if ((int)blockIdx.x * 256 >= n) return;
  const int i = blockIdx.x * 256 + threadIdx.x;
  float s = (i < n) ? fabsf(w[i]) : 0.f;
  s = block_reduce_sum(s, sm);
  if (threadIdx.x == 0) atomicAdd(&red[blockIdx.y * 4 + 0], s);
}

// phase2: alpha sums AND all weight packing (reuses the loaded value).
// q1t: fp32 sign, tap-major [tap=ic*9+kh*3+kw][oc]  (conv1)
// bp2/bp3: bf16 sign, k=(kh*3+kw)*CIN+ic, dest ((k>>3)*COUT+n)*8+(k&7)
// ql: fp32 sign (alpha applied in linear via red)
__global__ __launch_bounds__(256) void tern_phase2(
    const float* w0, const float* w1, const float* w2, const float* w3,
    int n0, int n1, int n2, int n3, float* __restrict__ red,
    float* __restrict__ q1t, unsigned short* __restrict__ bp2,
    unsigned short* __restrict__ bp3, float* __restrict__ ql) {
  __shared__ float sm[8];
  const float* w; int n;
  const int by = blockIdx.y;
  tsel(by, w0, w1, w2, w3, n0, n1, n2, n3, w, n);
  if ((int)blockIdx.x * 256 >= n) return;
  const float delta = 0.7f * red[by * 4 + 0] / (float)n;
  const int i = blockIdx.x * 256 + threadIdx.x;
  float c = 0.f, a = 0.f;
  float wv = 0.f;
  if (i < n) {
    wv = w[i];
    const float av = fabsf(wv);
    if (av > delta) { c = 1.f; a = av; }
  }
  // ---- pack (independent of the reductions)
  if (i < n) {
    const float sgnf = (wv > delta) ? 1.f : (wv < -delta ? -1.f : 0.f);
    const unsigned short sgnb =
        (wv > delta) ? 0x3F80u : (wv < -delta ? 0xBF80u : 0u);
    if (by == 0) {
      q1t[(i % 27) * 32 + i / 27] = sgnf;
    } else if (by == 1) {
      const int k = (i % 9) * 32 + (i % 288) / 9;
      bp2[((size_t)(k >> 3) * 64 + i / 288) * 8 + (k & 7)] = sgnb;
    } else if (by == 2) {
      const int k = (i % 9) * 64 + (i % 576) / 9;
      bp3[((size_t)(k >> 3) * 128 + i / 576) * 8 + (k & 7)] = sgnb;
    } else {
      ql[i] = sgnf;
    }
  }
  c = block_reduce_sum(c, sm);
  a = block_reduce_sum(a, sm);
  if (threadIdx.x == 0) {
    atomicAdd(&red[by * 4 + 1], c);
    atomicAdd(&red[by * 4 + 2], a);
  }
}

// ---------------------------------------------------------------- conv1
// Direct fp32, stride 2, pad 1. BN fold (alpha1 included) computed inline.
__global__ __launch_bounds__(256) void conv1_v2(
    const float* __restrict__ x, const float* __restrict__ q1t,
    const float* __restrict__ red,
    const float* __restrict__ g1, const float* __restrict__ b1,
    const float* __restrict__ m1, const float* __restrict__ v1,
    unsigned short* __restrict__ y) {
  __shared__ float xs[15 * 225];  // [ic*5 + dr][slot], slot = iw+1
  __shared__ float s1L[32], b1L[32];
  const int n = blockIdx.y;
  const int oh0 = blockIdx.x * 2;
  const int t = threadIdx.x;
  if (t < 32) {
    const float inv = g1[t] / sqrtf(v1[t] + 1e-5f);
    const float a1 = red[2] / fmaxf(red[1], 1.f);
    s1L[t] = a1 * inv;
    b1L[t] = b1[t] - m1[t] * inv;
  }
  const int ih_base = oh0 * 2 - 1;
  for (int idx = t; idx < 15 * 225; idx += 256) {
    const int row = idx / 225, s = idx % 225;
    const int ic = row / 5, dr = row % 5;
    const int ih = ih_base + dr, iw = s - 1;
    float v = 0.f;
    if ((unsigned)ih < 224u && (unsigned)iw < 224u)
      v = x[((size_t)n * 3 + ic) * 50176 + (size_t)ih * 224 + iw];
    xs[idx] = v;
  }
  __syncthreads();
  if (t >= 224) return;
  const int r = t / 112, ow = t % 112;
  float acc[32];
#pragma unroll
  for (int j = 0; j < 32; ++j) acc[j] = 0.f;
#pragma unroll
  for (int ic = 0; ic < 3; ++ic)
#pragma unroll
    for (int kh = 0; kh < 3; ++kh) {
      const float* xr = &xs[(ic * 5 + r * 2 + kh) * 225 + 2 * ow];
      const float xv0 = xr[0], xv1 = xr[1], xv2 = xr[2];
#pragma unroll
      for (int kw = 0; kw < 3; ++kw) {
        const float xv = (kw == 0) ? xv0 : (kw == 1) ? xv1 : xv2;
        const float* wrow = &q1t[(ic * 9 + kh * 3 + kw) * 32];
#pragma unroll
        for (int j = 0; j < 32; ++j) acc[j] += xv * wrow[j];
      }
    }
  const int oh = oh0 + r;
  unsigned pk[16];
#pragma unroll
  for (int h = 0; h < 16; ++h) {
    const float a0 = fmaxf(acc[2 * h] * s1L[2 * h] + b1L[2 * h], 0.f);
    const float a1 = fmaxf(acc[2 * h + 1] * s1L[2 * h + 1] + b1L[2 * h + 1], 0.f);
    pk[h] = (unsigned)f2bf(a0) | ((unsigned)f2bf(a1) << 16);
  }
  unsigned short* dst = y + (((size_t)n * 112 + oh) * 112 + ow) * 32;
#pragma unroll
  for (int v = 0; v < 4; ++v)
    *(uint4*)(dst + v * 8) = make_uint4(pk[4 * v], pk[4 * v + 1],
                                        pk[4 * v + 2], pk[4 * v + 3]);
}

// ---------------------------------------------------------------- conv2 (persistent halo)
// Grid-stride over 6272 tiles (8x16 px x 64 och); 1568 blocks x 4 tiles.
// Stores of tile i drain while tile i+1 stages. BN fold inline per lane.
__global__ __launch_bounds__(256, 6) void conv2_halo(
    const unsigned short* __restrict__ xin,
    const unsigned short* __restrict__ bp,
    const float* __restrict__ red,
    const float* __restrict__ g2, const float* __restrict__ b2,
    const float* __restrict__ m2, const float* __restrict__ v2,
    unsigned short* __restrict__ yout) {
  constexpr int PH = 10, PW = 18;
  __shared__ unsigned short patch[4 * PH * PW * 8];
  const int t = threadIdx.x;
  const int wave = t >> 6, lane = t & 63, quad = lane >> 4, l16 = lane & 15;

  float sc[4], bs[4];
  const float a2 = red[6] / fmaxf(red[5], 1.f);
#pragma unroll
  for (int nf = 0; nf < 4; ++nf) {
    const int ch = nf * 16 + l16;
    const float inv = g2[ch] / sqrtf(v2[ch] + 1e-5f);
    sc[nf] = a2 * inv;
    bs[nf] = b2[ch] - m2[ch] * inv;
  }

  for (int tile = blockIdx.x; tile < 6272; tile += 1568) {
    const int img = tile / 98, t2 = tile % 98;
    const int oh0 = (t2 / 7) * 8, ow0 = (t2 % 7) * 16;
    __syncthreads();  // previous tile's patch reads done
    for (int c = t; c < PH * PW * 4; c += 256) {
      const int pix = c >> 2, seg = c & 3;
      const int pi = pix / PW, pj = pix % PW;
      const int ih = oh0 - 1 + pi, iw = ow0 - 1 + pj;
      uint4 v = make_uint4(0u, 0u, 0u, 0u);
      if ((unsigned)ih < 112u && (unsigned)iw < 112u)
        v = *(const uint4*)(xin + (((size_t)img * 112 + ih) * 112 + iw) * 32 +
                            seg * 8);
      *(uint4*)(&patch[((seg * PH + pi) * PW + pj) * 8]) = v;
    }

    floatx4 acc[2][4];
#pragma unroll
    for (int mf = 0; mf < 2; ++mf)
#pragma unroll
      for (int nf = 0; nf < 4; ++nf) acc[mf][nf] = (floatx4){0.f, 0.f, 0.f, 0.f};

    short8 bcur[4], bnxt[4];
#pragma unroll
    for (int nf = 0; nf < 4; ++nf)
      bcur[nf] = *(const short8*)(bp + ((size_t)quad * 64 + nf * 16 + l16) * 8);
    __syncthreads();  // patch visible

#pragma unroll
    for (int tap = 0; tap < 9; ++tap) {
      const int kh = tap / 3, kw = tap % 3;
      if (tap + 1 < 9) {
        const int kg = (tap + 1) * 4 + quad;
#pragma unroll
        for (int nf = 0; nf < 4; ++nf)
          bnxt[nf] = *(const short8*)(bp + ((size_t)kg * 64 + nf * 16 + l16) * 8);
      }
#pragma unroll
      for (int mf = 0; mf < 2; ++mf) {
        const int pi = (wave * 2 + mf) + kh;
        const short8 a = *(const short8*)(
            &patch[((quad * PH + pi) * PW + l16 + kw) * 8]);
#pragma unroll
        for (int nf = 0; nf < 4; ++nf)
          acc[mf][nf] = __builtin_amdgcn_mfma_f32_16x16x32_bf16(
              a, bcur[nf], acc[mf][nf], 0, 0, 0);
      }
#pragma unroll
      for (int nf = 0; nf < 4; ++nf) bcur[nf] = bnxt[nf];
    }

#pragma unroll
    for (int mf = 0; mf < 2; ++mf) {
      const int oh = oh0 + wave * 2 + mf;
#pragma unroll
      for (int r = 0; r < 4; ++r) {
        const int ow = ow0 + quad * 4 + r;
        const size_t base = (((size_t)img * 112 + oh) * 112 + ow) * 64;
#pragma unroll
        for (int nf = 0; nf < 4; ++nf) {
          const float vv = fmaxf(acc[mf][nf][r] * sc[nf] + bs[nf], 0.f);
          yout[base + nf * 16 + l16] = f2bf(vv);
        }
      }
    }
  }
}

// ---------------------------------------------------------------- conv3+pool (persistent)
// Grid-stride over 3136 tiles (8x8 conv3 px x 128 och); 1568 blocks x 2.
// Patch 17x17x32 per ic-half, parity-split seg-major LDS (verified R8/R9).
// BN fold inline; pool fused (1 atomic/ch/tile).
__global__ __launch_bounds__(256, 5) void conv3_pool(
    const unsigned short* __restrict__ act2,
    const unsigned short* __restrict__ bp3,
    const float* __restrict__ red,
    const float* __restrict__ g3, const float* __restrict__ b3,
    const float* __restrict__ m3, const float* __restrict__ v3,
    float* __restrict__ pooled) {
  __shared__ unsigned short c2p[4 * 17 * 18 * 8];  // 19584 B
  __shared__ float pbuf[128];
  const int t = threadIdx.x;
  const int wave = t >> 6, lane = t & 63, quad = lane >> 4, l16 = lane & 15;

  float sc3[2], bs3[2];
  const float a3 = red[10] / fmaxf(red[9], 1.f);
#pragma unroll
  for (int nf = 0; nf < 2; ++nf) {
    const int ch = wave * 32 + nf * 16 + l16;
    const float inv = g3[ch] / sqrtf(v3[ch] + 1e-5f);
    sc3[nf] = a3 * inv;
    bs3[nf] = b3[ch] - m3[ch] * inv;
  }

  int a3off[4];
#pragma unroll
  for (int mf = 0; mf < 4; ++mf) {
    const int px = mf * 16 + l16;
    a3off[mf] = ((quad * 17 + (px >> 3) * 2) * 18 + (px & 7)) * 8;
  }

  for (int tile = blockIdx.x; tile < 3136; tile += 1568) {
    const int img = tile / 49, tt = tile % 49;
    const int o3h0 = (tt / 7) * 8, o3w0 = (tt % 7) * 8;
    const int h0 = o3h0 * 2 - 1, w0 = o3w0 * 2 - 1;

    floatx4 acc3[4][2];
#pragma unroll
    for (int mf = 0; mf < 4; ++mf) {
      acc3[mf][0] = (floatx4){0.f, 0.f, 0.f, 0.f};
      acc3[mf][1] = (floatx4){0.f, 0.f, 0.f, 0.f};
    }

#pragma unroll
    for (int h = 0; h < 2; ++h) {
      __syncthreads();  // previous phase's c2p reads / pbuf reads done
      for (int c = t; c < 17 * 17 * 4; c += 256) {
        const int pix = c >> 2, seg = c & 3;
        const int pi = pix / 17, pj = pix % 17;
        const int ih = h0 + pi, iw = w0 + pj;
        uint4 v = make_uint4(0u, 0u, 0u, 0u);
        if ((unsigned)ih < 112u && (unsigned)iw < 112u)
          v = *(const uint4*)(act2 +
                              (((size_t)img * 112 + ih) * 112 + iw) * 64 +
                              h * 32 + seg * 8);
        const int slot = (pj >> 1) + (pj & 1) * 9;  // parity split (stride 2)
        *(uint4*)(&c2p[((seg * 17 + pi) * 18 + slot) * 8]) = v;
      }
      __syncthreads();
#pragma unroll
      for (int tap = 0; tap < 9; ++tap) {
        const int kh = tap / 3, kw = tap % 3;
        const int kg = tap * 8 + h * 4 + quad;
        const short8 b0 = *(const short8*)(
            bp3 + ((size_t)kg * 128 + wave * 32 + l16) * 8);
        const short8 b1 = *(const short8*)(
            bp3 + ((size_t)kg * 128 + wave * 32 + 16 + l16) * 8);
        const int toff = (kh * 18 + (kw >> 1) + (kw & 1) * 9) * 8;
#pragma unroll
        for (int mf = 0; mf < 4; ++mf) {
          const short8 a = *(const short8*)(&c2p[a3off[mf] + toff]);
          acc3[mf][0] = __builtin_amdgcn_mfma_f32_16x16x32_bf16(
              a, b0, acc3[mf][0], 0, 0, 0);
          acc3[mf][1] = __builtin_amdgcn_mfma_f32_16x16x32_bf16(
              a, b1, acc3[mf][1], 0, 0, 0);
        }
      }
    }

    // ---- BN3 + ReLU + pool (waves own disjoint 32-ch slices)
#pragma unroll
    for (int nf = 0; nf < 2; ++nf) {
      const int ch = wave * 32 + nf * 16 + l16;
      float s = 0.f;
#pragma unroll
      for (int mf = 0; mf < 4; ++mf)
#pragma unroll
        for (int r = 0; r < 4; ++r)
          s += fmaxf(acc3[mf][nf][r] * sc3[nf] + bs3[nf], 0.f);
      s += __shfl_xor(s, 16);
      s += __shfl_xor(s, 32);
      if (lane < 16) pbuf[ch] = s;
    }
    __syncthreads();
    if (t < 128) atomicAdd(&pooled[(size_t)img * 128 + t], pbuf[t]);
  }
}

// ---------------------------------------------------------------- linear
// pooled holds SUMS over 3136 px; ql holds signs; alpha_l from red.
__global__ void linear_kernel(const float* __restrict__ pooled,
                              const float* __restrict__ ql,
                              const float* __restrict__ bl,
                              const float* __restrict__ red,
                              float* __restrict__ out) {
  const int idx = blockIdx.x * blockDim.x + threadIdx.x;
  if (idx >= 64 * 10) return;
  const int n = idx / 10, o = idx % 10;
  const float* p = pooled + (size_t)n * 128;
  const float* w = ql + (size_t)o * 128;
  float s = 0.f;
#pragma unroll 4
  for (int c = 0; c < 128; ++c) s += p[c] * w[c];
  const float alpha_l = red[14] / fmaxf(red[13], 1.f);
  out[idx] = s * (alpha_l / 3136.f) + bl[o];
}

// ---------------------------------------------------------------- launch
extern "C" void kernel_launch(void* const* d_in, const int* in_sizes, int n_in,
                              void* d_out, int out_size, void* d_ws,
                              size_t ws_size, hipStream_t stream) {
  const float* x  = (const float*)d_in[0];
  const float* w1 = (const float*)d_in[1];
  const float* g1 = (const float*)d_in[2];
  const float* b1 = (const float*)d_in[3];
  const float* m1 = (const float*)d_in[4];
  const float* v1 = (const float*)d_in[5];
  const float* w2 = (const float*)d_in[6];
  const float* g2 = (const float*)d_in[7];
  const float* b2 = (const float*)d_in[8];
  const float* m2 = (const float*)d_in[9];
  const float* v2 = (const float*)d_in[10];
  const float* w3 = (const float*)d_in[11];
  const float* g3 = (const float*)d_in[12];
  const float* b3 = (const float*)d_in[13];
  const float* m3 = (const float*)d_in[14];
  const float* v3 = (const float*)d_in[15];
  const float* wl = (const float*)d_in[16];
  const float* bl = (const float*)d_in[17];
  float* out = (float*)d_out;

  // ---- workspace layout ----
  float* Wf = (float*)d_ws;
  float* red = Wf;                // 16
  float* pooled = red + 16;       // 8192 (zeroed with red in one memset)
  float* q1t = pooled + 8192;     // 864
  float* ql = q1t + 864;          // 1280
  unsigned short* Us = (unsigned short*)(ql + 1280);
  unsigned short* bp2 = Us;                 // 18432
  unsigned short* bp3 = bp2 + 18432;        // 73728
  unsigned short* act1 = bp3 + 73728;       // 64*12544*32 = 25690112
  unsigned short* act2 = act1 + 25690112;   // 64*12544*64 = 51380224
  // total ~155 MB < ws_size

  // ---- prep: 3 dispatches (memset + 2 reduction/pack phases) ----
  hipMemsetAsync(red, 0, (16 + 8192) * sizeof(float), stream);
  tern_phase1<<<dim3(288, 4), 256, 0, stream>>>(w1, w2, w3, wl, 864, 18432,
                                                73728, 1280, red);
  tern_phase2<<<dim3(288, 4), 256, 0, stream>>>(w1, w2, w3, wl, 864, 18432,
                                                73728, 1280, red, q1t, bp2,
                                                bp3, ql);

  // ---- network ----
  conv1_v2<<<dim3(56, 64), 256, 0, stream>>>(x, q1t, red, g1, b1, m1, v1,
                                             act1);
  conv2_halo<<<1568, 256, 0, stream>>>(act1, bp2, red, g2, b2, m2, v2, act2);
  conv3_pool<<<1568, 256, 0, stream>>>(act2, bp3, red, g3, b3, m3, v3,
                                       pooled);
  linear_kernel<<<3, 256, 0, stream>>>(pooled, ql, bl, red, out);
}

// Round 12
// 553.404 us; speedup vs baseline: 1.4313x; 1.4313x over previous
//
#include <hip/hip_runtime.h>
#include <cstddef>

typedef __attribute__((ext_vector_type(8))) short short8;
typedef __attribute__((ext_vector_type(4))) float floatx4;

// ---------------------------------------------------------------- bf16 utils
__device__ __forceinline__ unsigned short f2bf(float f) {
  union { float f; unsigned u; } v; v.f = f;
  const unsigned r = v.u + 0x7fffu + ((v.u >> 16) & 1u);  // RNE
  return (unsigned short)(r >> 16);
}

// ---------------------------------------------------------------- reductions
__device__ __forceinline__ float block_reduce_sum(float v, float* sm) {
#pragma unroll
  for (int off = 32; off > 0; off >>= 1) v += __shfl_down(v, off, 64);
  const int lane = threadIdx.x & 63, wid = threadIdx.x >> 6;
  __syncthreads();
  if (lane == 0) sm[wid] = v;
  __syncthreads();
  if (threadIdx.x == 0) {
    float t = 0.f;
    const int nw = (blockDim.x + 63) >> 6;
    for (int i = 0; i < nw; ++i) t += sm[i];
    sm[0] = t;
  }
  __syncthreads();
  return sm[0];
}

// ---------------------------------------------------------------- ternarize
// red[t*4+0]=sum|w|, red[t*4+1]=masked count, red[t*4+2]=masked sum|w|.
__device__ __forceinline__ void tsel(int t, const float* w0, const float* w1,
                                     const float* w2, const float* w3, int n0,
                                     int n1, int n2, int n3,
                                     const float*& w, int& n) {
  w = (t == 0) ? w0 : (t == 1) ? w1 : (t == 2) ? w2 : w3;
  n = (t == 0) ? n0 : (t == 1) ? n1 : (t == 2) ? n2 : n3;
}

__global__ __launch_bounds__(256) void tern_phase1(
    const float* w0, const float* w1, const float* w2, const float* w3,
    int n0, int n1, int n2, int n3, float* __restrict__ red) {
  __shared__ float sm[8];
  const float* w; int n;
  tsel(blockIdx.y, w0, w1, w2, w3, n0, n1, n2, n3, w, n);
  if ((int)blockIdx.x * 256 >= n) return;
  const int i = blockIdx.x * 256 + threadIdx.x;
  float s = (i < n) ? fabsf(w[i]) : 0.f;
  s = block_reduce_sum(s, sm);
  if (threadIdx.x == 0) atomicAdd(&red[blockIdx.y * 4 + 0], s);
}

// phase2: alpha sums AND all weight packing (reuses the loaded value).
// q1t: fp32 sign, tap-major [tap=ic*9+kh*3+kw][oc]  (conv1)
// bp2/bp3: bf16 sign, k=(kh*3+kw)*CIN+ic, dest ((k>>3)*COUT+n)*8+(k&7)
// ql: fp32 sign (alpha applied in linear via red)
__global__ __launch_bounds__(256) void tern_phase2(
    const float* w0, const float* w1, const float* w2, const float* w3,
    int n0, int n1, int n2, int n3, float* __restrict__ red,
    float* __restrict__ q1t, unsigned short* __restrict__ bp2,
    unsigned short* __restrict__ bp3, float* __restrict__ ql) {
  __shared__ float sm[8];
  const float* w; int n;
  const int by = blockIdx.y;
  tsel(by, w0, w1, w2, w3, n0, n1, n2, n3, w, n);
  if ((int)blockIdx.x * 256 >= n) return;
  const float delta = 0.7f * red[by * 4 + 0] / (float)n;
  const int i = blockIdx.x * 256 + threadIdx.x;
  float c = 0.f, a = 0.f;
  float wv = 0.f;
  if (i < n) {
    wv = w[i];
    const float av = fabsf(wv);
    if (av > delta) { c = 1.f; a = av; }
  }
  // ---- pack (independent of the reductions)
  if (i < n) {
    const float sgnf = (wv > delta) ? 1.f : (wv < -delta ? -1.f : 0.f);
    const unsigned short sgnb =
        (wv > delta) ? 0x3F80u : (wv < -delta ? 0xBF80u : 0u);
    if (by == 0) {
      q1t[(i % 27) * 32 + i / 27] = sgnf;
    } else if (by == 1) {
      const int k = (i % 9) * 32 + (i % 288) / 9;
      bp2[((size_t)(k >> 3) * 64 + i / 288) * 8 + (k & 7)] = sgnb;
    } else if (by == 2) {
      const int k = (i % 9) * 64 + (i % 576) / 9;
      bp3[((size_t)(k >> 3) * 128 + i / 576) * 8 + (k & 7)] = sgnb;
    } else {
      ql[i] = sgnf;
    }
  }
  c = block_reduce_sum(c, sm);
  a = block_reduce_sum(a, sm);
  if (threadIdx.x == 0) {
    atomicAdd(&red[by * 4 + 1], c);
    atomicAdd(&red[by * 4 + 2], a);
  }
}

// ---------------------------------------------------------------- conv1
// Direct fp32, stride 2, pad 1. BN fold (alpha1 included) computed inline.
__global__ __launch_bounds__(256) void conv1_v2(
    const float* __restrict__ x, const float* __restrict__ q1t,
    const float* __restrict__ red,
    const float* __restrict__ g1, const float* __restrict__ b1,
    const float* __restrict__ m1, const float* __restrict__ v1,
    unsigned short* __restrict__ y) {
  __shared__ float xs[15 * 225];  // [ic*5 + dr][slot], slot = iw+1
  __shared__ float s1L[32], b1L[32];
  const int n = blockIdx.y;
  const int oh0 = blockIdx.x * 2;
  const int t = threadIdx.x;
  if (t < 32) {
    const float inv = g1[t] / sqrtf(v1[t] + 1e-5f);
    const float a1 = red[2] / fmaxf(red[1], 1.f);
    s1L[t] = a1 * inv;
    b1L[t] = b1[t] - m1[t] * inv;
  }
  const int ih_base = oh0 * 2 - 1;
  for (int idx = t; idx < 15 * 225; idx += 256) {
    const int row = idx / 225, s = idx % 225;
    const int ic = row / 5, dr = row % 5;
    const int ih = ih_base + dr, iw = s - 1;
    float v = 0.f;
    if ((unsigned)ih < 224u && (unsigned)iw < 224u)
      v = x[((size_t)n * 3 + ic) * 50176 + (size_t)ih * 224 + iw];
    xs[idx] = v;
  }
  __syncthreads();
  if (t >= 224) return;
  const int r = t / 112, ow = t % 112;
  float acc[32];
#pragma unroll
  for (int j = 0; j < 32; ++j) acc[j] = 0.f;
#pragma unroll
  for (int ic = 0; ic < 3; ++ic)
#pragma unroll
    for (int kh = 0; kh < 3; ++kh) {
      const float* xr = &xs[(ic * 5 + r * 2 + kh) * 225 + 2 * ow];
      const float xv0 = xr[0], xv1 = xr[1], xv2 = xr[2];
#pragma unroll
      for (int kw = 0; kw < 3; ++kw) {
        const float xv = (kw == 0) ? xv0 : (kw == 1) ? xv1 : xv2;
        const float* wrow = &q1t[(ic * 9 + kh * 3 + kw) * 32];
#pragma unroll
        for (int j = 0; j < 32; ++j) acc[j] += xv * wrow[j];
      }
    }
  const int oh = oh0 + r;
  unsigned pk[16];
#pragma unroll
  for (int h = 0; h < 16; ++h) {
    const float a0 = fmaxf(acc[2 * h] * s1L[2 * h] + b1L[2 * h], 0.f);
    const float a1 = fmaxf(acc[2 * h + 1] * s1L[2 * h + 1] + b1L[2 * h + 1], 0.f);
    pk[h] = (unsigned)f2bf(a0) | ((unsigned)f2bf(a1) << 16);
  }
  unsigned short* dst = y + (((size_t)n * 112 + oh) * 112 + ow) * 32;
#pragma unroll
  for (int v = 0; v < 4; ++v)
    *(uint4*)(dst + v * 8) = make_uint4(pk[4 * v], pk[4 * v + 1],
                                        pk[4 * v + 2], pk[4 * v + 3]);
}

// ---------------------------------------------------------------- conv2 (persistent halo)
// Grid-stride over 6272 tiles (8x16 px x 64 och); 1568 blocks x 4 tiles.
// __launch_bounds__(256, 4): 128-VGPR budget. R11's (256,6) forced 40 VGPRs
// -> accumulator scratch spill -> 1.3 GB HBM traffic, 8x regression. The
// bound must leave room for the ~64-80 reg working set (acc 32 + b-frags 16
// + staging).
__global__ __launch_bounds__(256, 4) void conv2_halo(
    const unsigned short* __restrict__ xin,
    const unsigned short* __restrict__ bp,
    const float* __restrict__ red,
    const float* __restrict__ g2, const float* __restrict__ b2,
    const float* __restrict__ m2, const float* __restrict__ v2,
    unsigned short* __restrict__ yout) {
  constexpr int PH = 10, PW = 18;
  __shared__ unsigned short patch[4 * PH * PW * 8];
  const int t = threadIdx.x;
  const int wave = t >> 6, lane = t & 63, quad = lane >> 4, l16 = lane & 15;

  float sc[4], bs[4];
  const float a2 = red[6] / fmaxf(red[5], 1.f);
#pragma unroll
  for (int nf = 0; nf < 4; ++nf) {
    const int ch = nf * 16 + l16;
    const float inv = g2[ch] / sqrtf(v2[ch] + 1e-5f);
    sc[nf] = a2 * inv;
    bs[nf] = b2[ch] - m2[ch] * inv;
  }

  for (int tile = blockIdx.x; tile < 6272; tile += 1568) {
    const int img = tile / 98, t2 = tile % 98;
    const int oh0 = (t2 / 7) * 8, ow0 = (t2 % 7) * 16;
    __syncthreads();  // previous tile's patch reads done
    for (int c = t; c < PH * PW * 4; c += 256) {
      const int pix = c >> 2, seg = c & 3;
      const int pi = pix / PW, pj = pix % PW;
      const int ih = oh0 - 1 + pi, iw = ow0 - 1 + pj;
      uint4 v = make_uint4(0u, 0u, 0u, 0u);
      if ((unsigned)ih < 112u && (unsigned)iw < 112u)
        v = *(const uint4*)(xin + (((size_t)img * 112 + ih) * 112 + iw) * 32 +
                            seg * 8);
      *(uint4*)(&patch[((seg * PH + pi) * PW + pj) * 8]) = v;
    }

    floatx4 acc[2][4];
#pragma unroll
    for (int mf = 0; mf < 2; ++mf)
#pragma unroll
      for (int nf = 0; nf < 4; ++nf) acc[mf][nf] = (floatx4){0.f, 0.f, 0.f, 0.f};

    short8 bcur[4], bnxt[4];
#pragma unroll
    for (int nf = 0; nf < 4; ++nf)
      bcur[nf] = *(const short8*)(bp + ((size_t)quad * 64 + nf * 16 + l16) * 8);
    __syncthreads();  // patch visible

#pragma unroll
    for (int tap = 0; tap < 9; ++tap) {
      const int kh = tap / 3, kw = tap % 3;
      if (tap + 1 < 9) {
        const int kg = (tap + 1) * 4 + quad;
#pragma unroll
        for (int nf = 0; nf < 4; ++nf)
          bnxt[nf] = *(const short8*)(bp + ((size_t)kg * 64 + nf * 16 + l16) * 8);
      }
#pragma unroll
      for (int mf = 0; mf < 2; ++mf) {
        const int pi = (wave * 2 + mf) + kh;
        const short8 a = *(const short8*)(
            &patch[((quad * PH + pi) * PW + l16 + kw) * 8]);
#pragma unroll
        for (int nf = 0; nf < 4; ++nf)
          acc[mf][nf] = __builtin_amdgcn_mfma_f32_16x16x32_bf16(
              a, bcur[nf], acc[mf][nf], 0, 0, 0);
      }
#pragma unroll
      for (int nf = 0; nf < 4; ++nf) bcur[nf] = bnxt[nf];
    }

#pragma unroll
    for (int mf = 0; mf < 2; ++mf) {
      const int oh = oh0 + wave * 2 + mf;
#pragma unroll
      for (int r = 0; r < 4; ++r) {
        const int ow = ow0 + quad * 4 + r;
        const size_t base = (((size_t)img * 112 + oh) * 112 + ow) * 64;
#pragma unroll
        for (int nf = 0; nf < 4; ++nf) {
          const float vv = fmaxf(acc[mf][nf][r] * sc[nf] + bs[nf], 0.f);
          yout[base + nf * 16 + l16] = f2bf(vv);
        }
      }
    }
  }
}

// ---------------------------------------------------------------- conv3+pool (persistent)
// Grid-stride over 3136 tiles (8x8 conv3 px x 128 och); 1568 blocks x 2.
// Patch 17x17x32 per ic-half, parity-split seg-major LDS (verified R8/R9).
// BN fold inline; pool fused (1 atomic/ch/tile). (256,5) verified spill-free
// in R9 (48 VGPR).
__global__ __launch_bounds__(256, 5) void conv3_pool(
    const unsigned short* __restrict__ act2,
    const unsigned short* __restrict__ bp3,
    const float* __restrict__ red,
    const float* __restrict__ g3, const float* __restrict__ b3,
    const float* __restrict__ m3, const float* __restrict__ v3,
    float* __restrict__ pooled) {
  __shared__ unsigned short c2p[4 * 17 * 18 * 8];  // 19584 B
  __shared__ float pbuf[128];
  const int t = threadIdx.x;
  const int wave = t >> 6, lane = t & 63, quad = lane >> 4, l16 = lane & 15;

  float sc3[2], bs3[2];
  const float a3 = red[10] / fmaxf(red[9], 1.f);
#pragma unroll
  for (int nf = 0; nf < 2; ++nf) {
    const int ch = wave * 32 + nf * 16 + l16;
    const float inv = g3[ch] / sqrtf(v3[ch] + 1e-5f);
    sc3[nf] = a3 * inv;
    bs3[nf] = b3[ch] - m3[ch] * inv;
  }

  int a3off[4];
#pragma unroll
  for (int mf = 0; mf < 4; ++mf) {
    const int px = mf * 16 + l16;
    a3off[mf] = ((quad * 17 + (px >> 3) * 2) * 18 + (px & 7)) * 8;
  }

  for (int tile = blockIdx.x; tile < 3136; tile += 1568) {
    const int img = tile / 49, tt = tile % 49;
    const int o3h0 = (tt / 7) * 8, o3w0 = (tt % 7) * 8;
    const int h0 = o3h0 * 2 - 1, w0 = o3w0 * 2 - 1;

    floatx4 acc3[4][2];
#pragma unroll
    for (int mf = 0; mf < 4; ++mf) {
      acc3[mf][0] = (floatx4){0.f, 0.f, 0.f, 0.f};
      acc3[mf][1] = (floatx4){0.f, 0.f, 0.f, 0.f};
    }

#pragma unroll
    for (int h = 0; h < 2; ++h) {
      __syncthreads();  // previous phase's c2p reads / pbuf reads done
      for (int c = t; c < 17 * 17 * 4; c += 256) {
        const int pix = c >> 2, seg = c & 3;
        const int pi = pix / 17, pj = pix % 17;
        const int ih = h0 + pi, iw = w0 + pj;
        uint4 v = make_uint4(0u, 0u, 0u, 0u);
        if ((unsigned)ih < 112u && (unsigned)iw < 112u)
          v = *(const uint4*)(act2 +
                              (((size_t)img * 112 + ih) * 112 + iw) * 64 +
                              h * 32 + seg * 8);
        const int slot = (pj >> 1) + (pj & 1) * 9;  // parity split (stride 2)
        *(uint4*)(&c2p[((seg * 17 + pi) * 18 + slot) * 8]) = v;
      }
      __syncthreads();
#pragma unroll
      for (int tap = 0; tap < 9; ++tap) {
        const int kh = tap / 3, kw = tap % 3;
        const int kg = tap * 8 + h * 4 + quad;
        const short8 b0 = *(const short8*)(
            bp3 + ((size_t)kg * 128 + wave * 32 + l16) * 8);
        const short8 b1 = *(const short8*)(
            bp3 + ((size_t)kg * 128 + wave * 32 + 16 + l16) * 8);
        const int toff = (kh * 18 + (kw >> 1) + (kw & 1) * 9) * 8;
#pragma unroll
        for (int mf = 0; mf < 4; ++mf) {
          const short8 a = *(const short8*)(&c2p[a3off[mf] + toff]);
          acc3[mf][0] = __builtin_amdgcn_mfma_f32_16x16x32_bf16(
              a, b0, acc3[mf][0], 0, 0, 0);
          acc3[mf][1] = __builtin_amdgcn_mfma_f32_16x16x32_bf16(
              a, b1, acc3[mf][1], 0, 0, 0);
        }
      }
    }

    // ---- BN3 + ReLU + pool (waves own disjoint 32-ch slices)
#pragma unroll
    for (int nf = 0; nf < 2; ++nf) {
      const int ch = wave * 32 + nf * 16 + l16;
      float s = 0.f;
#pragma unroll
      for (int mf = 0; mf < 4; ++mf)
#pragma unroll
        for (int r = 0; r < 4; ++r)
          s += fmaxf(acc3[mf][nf][r] * sc3[nf] + bs3[nf], 0.f);
      s += __shfl_xor(s, 16);
      s += __shfl_xor(s, 32);
      if (lane < 16) pbuf[ch] = s;
    }
    __syncthreads();
    if (t < 128) atomicAdd(&pooled[(size_t)img * 128 + t], pbuf[t]);
  }
}

// ---------------------------------------------------------------- linear
// pooled holds SUMS over 3136 px; ql holds signs; alpha_l from red.
__global__ void linear_kernel(const float* __restrict__ pooled,
                              const float* __restrict__ ql,
                              const float* __restrict__ bl,
                              const float* __restrict__ red,
                              float* __restrict__ out) {
  const int idx = blockIdx.x * blockDim.x + threadIdx.x;
  if (idx >= 64 * 10) return;
  const int n = idx / 10, o = idx % 10;
  const float* p = pooled + (size_t)n * 128;
  const float* w = ql + (size_t)o * 128;
  float s = 0.f;
#pragma unroll 4
  for (int c = 0; c < 128; ++c) s += p[c] * w[c];
  const float alpha_l = red[14] / fmaxf(red[13], 1.f);
  out[idx] = s * (alpha_l / 3136.f) + bl[o];
}

// ---------------------------------------------------------------- launch
extern "C" void kernel_launch(void* const* d_in, const int* in_sizes, int n_in,
                              void* d_out, int out_size, void* d_ws,
                              size_t ws_size, hipStream_t stream) {
  const float* x  = (const float*)d_in[0];
  const float* w1 = (const float*)d_in[1];
  const float* g1 = (const float*)d_in[2];
  const float* b1 = (const float*)d_in[3];
  const float* m1 = (const float*)d_in[4];
  const float* v1 = (const float*)d_in[5];
  const float* w2 = (const float*)d_in[6];
  const float* g2 = (const float*)d_in[7];
  const float* b2 = (const float*)d_in[8];
  const float* m2 = (const float*)d_in[9];
  const float* v2 = (const float*)d_in[10];
  const float* w3 = (const float*)d_in[11];
  const float* g3 = (const float*)d_in[12];
  const float* b3 = (const float*)d_in[13];
  const float* m3 = (const float*)d_in[14];
  const float* v3 = (const float*)d_in[15];
  const float* wl = (const float*)d_in[16];
  const float* bl = (const float*)d_in[17];
  float* out = (float*)d_out;

  // ---- workspace layout ----
  float* Wf = (float*)d_ws;
  float* red = Wf;                // 16
  float* pooled = red + 16;       // 8192 (zeroed with red in one memset)
  float* q1t = pooled + 8192;     // 864
  float* ql = q1t + 864;          // 1280
  unsigned short* Us = (unsigned short*)(ql + 1280);
  unsigned short* bp2 = Us;                 // 18432
  unsigned short* bp3 = bp2 + 18432;        // 73728
  unsigned short* act1 = bp3 + 73728;       // 64*12544*32 = 25690112
  unsigned short* act2 = act1 + 25690112;   // 64*12544*64 = 51380224
  // total ~155 MB < ws_size

  // ---- prep: 3 dispatches (memset + 2 reduction/pack phases) ----
  hipMemsetAsync(red, 0, (16 + 8192) * sizeof(float), stream);
  tern_phase1<<<dim3(288, 4), 256, 0, stream>>>(w1, w2, w3, wl, 864, 18432,
                                                73728, 1280, red);
  tern_phase2<<<dim3(288, 4), 256, 0, stream>>>(w1, w2, w3, wl, 864, 18432,
                                                73728, 1280, red, q1t, bp2,
                                                bp3, ql);

  // ---- network ----
  conv1_v2<<<dim3(56, 64), 256, 0, stream>>>(x, q1t, red, g1, b1, m1, v1,
                                             act1);
  conv2_halo<<<1568, 256, 0, stream>>>(act1, bp2, red, g2, b2, m2, v2, act2);
  conv3_pool<<<1568, 256, 0, stream>>>(act2, bp3, red, g3, b3, m3, v3,
                                       pooled);
  linear_kernel<<<3, 256, 0, stream>>>(pooled, ql, bl, red, out);
}

// Round 13
// 258.472 us; speedup vs baseline: 3.0644x; 2.1411x over previous
//
#include <hip/hip_runtime.h>
#include <cstddef>

typedef __attribute__((ext_vector_type(8))) short short8;
typedef __attribute__((ext_vector_type(4))) float floatx4;

// ---------------------------------------------------------------- bf16 utils
__device__ __forceinline__ unsigned short f2bf(float f) {
  union { float f; unsigned u; } v; v.f = f;
  const unsigned r = v.u + 0x7fffu + ((v.u >> 16) & 1u);  // RNE
  return (unsigned short)(r >> 16);
}

// ---------------------------------------------------------------- reductions
__device__ __forceinline__ float block_reduce_sum(float v, float* sm) {
#pragma unroll
  for (int off = 32; off > 0; off >>= 1) v += __shfl_down(v, off, 64);
  const int lane = threadIdx.x & 63, wid = threadIdx.x >> 6;
  __syncthreads();
  if (lane == 0) sm[wid] = v;
  __syncthreads();
  if (threadIdx.x == 0) {
    float t = 0.f;
    const int nw = (blockDim.x + 63) >> 6;
    for (int i = 0; i < nw; ++i) t += sm[i];
    sm[0] = t;
  }
  __syncthreads();
  return sm[0];
}

// ---------------------------------------------------------------- ternarize
// red[t*4+0]=sum|w|, red[t*4+1]=masked count, red[t*4+2]=masked sum|w|.
__device__ __forceinline__ void tsel(int t, const float* w0, const float* w1,
                                     const float* w2, const float* w3, int n0,
                                     int n1, int n2, int n3,
                                     const float*& w, int& n) {
  w = (t == 0) ? w0 : (t == 1) ? w1 : (t == 2) ? w2 : w3;
  n = (t == 0) ? n0 : (t == 1) ? n1 : (t == 2) ? n2 : n3;
}

__global__ __launch_bounds__(256) void tern_phase1(
    const float* w0, const float* w1, const float* w2, const float* w3,
    int n0, int n1, int n2, int n3, float* __restrict__ red) {
  __shared__ float sm[8];
  const float* w; int n;
  tsel(blockIdx.y, w0, w1, w2, w3, n0, n1, n2, n3, w, n);
  if ((int)blockIdx.x * 256 >= n) return;
  const int i = blockIdx.x * 256 + threadIdx.x;
  float s = (i < n) ? fabsf(w[i]) : 0.f;
  s = block_reduce_sum(s, sm);
  if (threadIdx.x == 0) atomicAdd(&red[blockIdx.y * 4 + 0], s);
}

// phase2: alpha sums AND all weight packing (reuses the loaded value).
// bp1: conv1 signs, K=32 (27 taps + 5 zeros from memset), k=ic*9+kh*3+kw,
//      dest ((k>>3)*32 + oc)*8 + (k&7)  -> lane B/A-frag = one 16B load
// bp2/bp3: bf16 sign, k=(kh*3+kw)*CIN+ic, dest ((k>>3)*COUT+n)*8+(k&7)
// ql: fp32 sign (alpha applied in linear via red)
__global__ __launch_bounds__(256) void tern_phase2(
    const float* w0, const float* w1, const float* w2, const float* w3,
    int n0, int n1, int n2, int n3, float* __restrict__ red,
    unsigned short* __restrict__ bp1, unsigned short* __restrict__ bp2,
    unsigned short* __restrict__ bp3, float* __restrict__ ql) {
  __shared__ float sm[8];
  const float* w; int n;
  const int by = blockIdx.y;
  tsel(by, w0, w1, w2, w3, n0, n1, n2, n3, w, n);
  if ((int)blockIdx.x * 256 >= n) return;
  const float delta = 0.7f * red[by * 4 + 0] / (float)n;
  const int i = blockIdx.x * 256 + threadIdx.x;
  float c = 0.f, a = 0.f;
  float wv = 0.f;
  if (i < n) {
    wv = w[i];
    const float av = fabsf(wv);
    if (av > delta) { c = 1.f; a = av; }
  }
  // ---- pack (independent of the reductions)
  if (i < n) {
    const float sgnf = (wv > delta) ? 1.f : (wv < -delta ? -1.f : 0.f);
    const unsigned short sgnb =
        (wv > delta) ? 0x3F80u : (wv < -delta ? 0xBF80u : 0u);
    if (by == 0) {
      const int k = i % 27, oc = i / 27;  // w1 OIHW flat: oc*27 + (ic*9+kh*3+kw)
      bp1[((size_t)(k >> 3) * 32 + oc) * 8 + (k & 7)] = sgnb;
    } else if (by == 1) {
      const int k = (i % 9) * 32 + (i % 288) / 9;
      bp2[((size_t)(k >> 3) * 64 + i / 288) * 8 + (k & 7)] = sgnb;
    } else if (by == 2) {
      const int k = (i % 9) * 64 + (i % 576) / 9;
      bp3[((size_t)(k >> 3) * 128 + i / 576) * 8 + (k & 7)] = sgnb;
    } else {
      ql[i] = sgnf;
    }
  }
  c = block_reduce_sum(c, sm);
  a = block_reduce_sum(a, sm);
  if (threadIdx.x == 0) {
    atomicAdd(&red[by * 4 + 1], c);
    atomicAdd(&red[by * 4 + 2], a);
  }
}

// ---------------------------------------------------------------- BN fold
// One tiny block; alpha folded into every scale (all convs use sign weights).
__global__ void bnfold_all(
    const float* g1, const float* b1, const float* m1, const float* v1,
    const float* g2, const float* b2, const float* m2, const float* v2,
    const float* g3, const float* b3, const float* m3, const float* v3,
    float* s1, float* bb1, float* s2, float* bb2, float* s3, float* bb3,
    const float* __restrict__ red) {
  const int i = threadIdx.x;
  if (i < 32) {
    const float inv = g1[i] / sqrtf(v1[i] + 1e-5f);
    const float a = red[2] / fmaxf(red[1], 1.f);
    s1[i] = a * inv; bb1[i] = b1[i] - m1[i] * inv;
  } else if (i < 96) {
    const int c = i - 32;
    const float inv = g2[c] / sqrtf(v2[c] + 1e-5f);
    const float a = red[6] / fmaxf(red[5], 1.f);
    s2[c] = a * inv; bb2[c] = b2[c] - m2[c] * inv;
  } else if (i < 224) {
    const int c = i - 96;
    const float inv = g3[c] / sqrtf(v3[c] + 1e-5f);
    const float a = red[10] / fmaxf(red[9], 1.f);
    s3[c] = a * inv; bb3[c] = b3[c] - m3[c] * inv;
  }
}

// ---------------------------------------------------------------- conv1 (MFMA)
// Implicit GEMM: block = 8x16 output px tile of one image (grid 98 x 64).
// Stage fp32 patch 3x17x33 -> build bf16 im2col tile [128 px][K=32]
// (k=ic*9+kh*3+kw; k>=27 zero) in LDS, rows padded to 40 shorts (16B-aligned
// ds_read_b128, 2-way banks = free). Weights bp1 = K32 x N32 ternary signs,
// L1-hot 2KB, same k-inner-8 frag layout as conv2 (verified). C-layout
// epilogue identical to conv2's (verified). Replaces 864 scalar FMAs + 864
// weight loads per thread with ~16 LDS reads + 4 MFMAs.
__global__ __launch_bounds__(256) void conv1_mfma(
    const float* __restrict__ x, const unsigned short* __restrict__ bp1,
    const float* __restrict__ s1, const float* __restrict__ bb1,
    unsigned short* __restrict__ y) {
  __shared__ float xs[3 * 17 * 33];        // 6732 B
  __shared__ unsigned short im[128 * 40];  // 10240 B
  const int n = blockIdx.y;
  const int oh0 = (blockIdx.x / 7) * 8, ow0 = (blockIdx.x % 7) * 16;
  const int t = threadIdx.x;
  const int wave = t >> 6, lane = t & 63, quad = lane >> 4, l16 = lane & 15;

  // ---- stage input patch (zeros outside image); pad=1, stride=2
  const int ihb = oh0 * 2 - 1, iwb = ow0 * 2 - 1;
  for (int i = t; i < 1683; i += 256) {
    const int ic = i / 561, r2 = i % 561;
    const int pr = r2 / 33, pc = r2 % 33;
    const int ih = ihb + pr, iw = iwb + pc;
    float v = 0.f;
    if ((unsigned)ih < 224u && (unsigned)iw < 224u)
      v = x[((size_t)n * 3 + ic) * 50176 + (size_t)ih * 224 + iw];
    xs[i] = v;
  }
  __syncthreads();

  // ---- im2col: chunk = (px, seg) -> 8 bf16 k-values, one 16B write
#pragma unroll
  for (int cc = 0; cc < 2; ++cc) {
    const int c = cc * 256 + t;
    const int px = c >> 2, seg = c & 3;
    const int ohl = px >> 4, owl = px & 15;
    unsigned u[4];
#pragma unroll
    for (int jj = 0; jj < 4; ++jj) {
      unsigned short lo = 0, hi = 0;
      const int k0 = seg * 8 + 2 * jj, k1 = k0 + 1;
      if (k0 < 27) {
        const int ic = k0 / 9, tp = k0 % 9;
        lo = f2bf(xs[(ic * 17 + ohl * 2 + tp / 3) * 33 + owl * 2 + tp % 3]);
      }
      if (k1 < 27) {
        const int ic = k1 / 9, tp = k1 % 9;
        hi = f2bf(xs[(ic * 17 + ohl * 2 + tp / 3) * 33 + owl * 2 + tp % 3]);
      }
      u[jj] = (unsigned)lo | ((unsigned)hi << 16);
    }
    *(uint4*)(&im[px * 40 + seg * 8]) = make_uint4(u[0], u[1], u[2], u[3]);
  }

  // ---- B fragments (k = quad*8+j, n = nf*16+l16)
  short8 bfr[2];
#pragma unroll
  for (int nf = 0; nf < 2; ++nf)
    bfr[nf] = *(const short8*)(bp1 + ((size_t)quad * 32 + nf * 16 + l16) * 8);

  floatx4 acc[2][2];
#pragma unroll
  for (int mi = 0; mi < 2; ++mi) {
    acc[mi][0] = (floatx4){0.f, 0.f, 0.f, 0.f};
    acc[mi][1] = (floatx4){0.f, 0.f, 0.f, 0.f};
  }
  __syncthreads();

#pragma unroll
  for (int mi = 0; mi < 2; ++mi) {
    const int pxb = (wave * 2 + mi) * 16;
    const short8 a = *(const short8*)(&im[(pxb + l16) * 40 + quad * 8]);
#pragma unroll
    for (int nf = 0; nf < 2; ++nf)
      acc[mi][nf] = __builtin_amdgcn_mfma_f32_16x16x32_bf16(
          a, bfr[nf], acc[mi][nf], 0, 0, 0);
  }

  // ---- epilogue: BN1 + ReLU, NHWC bf16 (same pattern as conv2, verified)
  float sc[2], bs[2];
#pragma unroll
  for (int nf = 0; nf < 2; ++nf) {
    sc[nf] = s1[nf * 16 + l16];
    bs[nf] = bb1[nf * 16 + l16];
  }
#pragma unroll
  for (int mi = 0; mi < 2; ++mi) {
    const int oh = oh0 + wave * 2 + mi;
#pragma unroll
    for (int r = 0; r < 4; ++r) {
      const int ow = ow0 + quad * 4 + r;
      const size_t base = (((size_t)n * 112 + oh) * 112 + ow) * 32;
#pragma unroll
      for (int nf = 0; nf < 2; ++nf) {
        const float vv = fmaxf(acc[mi][nf][r] * sc[nf] + bs[nf], 0.f);
        y[base + nf * 16 + l16] = f2bf(vv);
      }
    }
  }
}

// ---------------------------------------------------------------- conv2 (halo)
// R9-EXACT. Block = 8x16 output tile x COUT=64. Patch in LDS once; B frags
// from global (L2-hot) prefetched one tap ahead. 1 barrier per block.
// NO extra launch_bounds / persistence: R11/R12 proved any tightening here
// spills the unified VGPR/AGPR file (457-730 MB scratch traffic).
__global__ __launch_bounds__(256) void conv2_halo(
    const unsigned short* __restrict__ xin,
    const unsigned short* __restrict__ bp,
    const float* __restrict__ scale, const float* __restrict__ bias,
    unsigned short* __restrict__ yout) {
  constexpr int PH = 10, PW = 18;
  __shared__ unsigned short patch[4 * PH * PW * 8];
  const int t = threadIdx.x;
  const int img = blockIdx.z;
  const int toh = blockIdx.x / 7, tow = blockIdx.x % 7;
  const int wave = t >> 6, lane = t & 63, quad = lane >> 4, l16 = lane & 15;
  const int oh0 = toh * 8, ow0 = tow * 16;

  for (int c = t; c < PH * PW * 4; c += 256) {
    const int pix = c >> 2, seg = c & 3;
    const int pi = pix / PW, pj = pix % PW;
    const int ih = oh0 - 1 + pi, iw = ow0 - 1 + pj;
    uint4 v = make_uint4(0u, 0u, 0u, 0u);
    if ((unsigned)ih < 112u && (unsigned)iw < 112u)
      v = *(const uint4*)(xin + (((size_t)img * 112 + ih) * 112 + iw) * 32 +
                          seg * 8);
    *(uint4*)(&patch[((seg * PH + pi) * PW + pj) * 8]) = v;
  }

  floatx4 acc[2][4];
#pragma unroll
  for (int mf = 0; mf < 2; ++mf)
#pragma unroll
    for (int nf = 0; nf < 4; ++nf) acc[mf][nf] = (floatx4){0.f, 0.f, 0.f, 0.f};

  short8 bcur[4], bnxt[4];
#pragma unroll
  for (int nf = 0; nf < 4; ++nf)
    bcur[nf] = *(const short8*)(bp + ((size_t)quad * 64 + nf * 16 + l16) * 8);
  __syncthreads();

#pragma unroll
  for (int tap = 0; tap < 9; ++tap) {
    const int kh = tap / 3, kw = tap % 3;
    if (tap + 1 < 9) {
      const int kg = (tap + 1) * 4 + quad;
#pragma unroll
      for (int nf = 0; nf < 4; ++nf)
        bnxt[nf] = *(const short8*)(bp + ((size_t)kg * 64 + nf * 16 + l16) * 8);
    }
#pragma unroll
    for (int mf = 0; mf < 2; ++mf) {
      const int pi = (wave * 2 + mf) + kh;
      const short8 a = *(const short8*)(
          &patch[((quad * PH + pi) * PW + l16 + kw) * 8]);
#pragma unroll
      for (int nf = 0; nf < 4; ++nf)
        acc[mf][nf] = __builtin_amdgcn_mfma_f32_16x16x32_bf16(
            a, bcur[nf], acc[mf][nf], 0, 0, 0);
    }
#pragma unroll
    for (int nf = 0; nf < 4; ++nf) bcur[nf] = bnxt[nf];
  }

  float sc[4], bs[4];
#pragma unroll
  for (int nf = 0; nf < 4; ++nf) {
    sc[nf] = scale[nf * 16 + l16];
    bs[nf] = bias[nf * 16 + l16];
  }
#pragma unroll
  for (int mf = 0; mf < 2; ++mf) {
    const int oh = oh0 + wave * 2 + mf;
#pragma unroll
    for (int r = 0; r < 4; ++r) {
      const int ow = ow0 + quad * 4 + r;
      const size_t base = (((size_t)img * 112 + oh) * 112 + ow) * 64;
#pragma unroll
      for (int nf = 0; nf < 4; ++nf) {
        const float vv = fmaxf(acc[mf][nf][r] * sc[nf] + bs[nf], 0.f);
        yout[base + nf * 16 + l16] = f2bf(vv);
      }
    }
  }
}

// ---------------------------------------------------------------- conv3+pool
// R9-EXACT. Block = one 8x8 conv3 output tile x all 128 och (grid 49 x 64).
// Patch 17x17x32 per ic-half, parity-split seg-major LDS; (256,5) verified
// spill-free at 48 VGPR. Pool fused: 1 atomic/ch/block.
__global__ __launch_bounds__(256, 5) void conv3_pool(
    const unsigned short* __restrict__ act2,
    const unsigned short* __restrict__ bp3,
    const float* __restrict__ s3, const float* __restrict__ bb3,
    float* __restrict__ pooled) {
  __shared__ unsigned short c2p[4 * 17 * 18 * 8];  // 19584 B
  __shared__ float pbuf[128];
  const int t = threadIdx.x;
  const int img = blockIdx.y;
  const int ty = blockIdx.x / 7, tx = blockIdx.x % 7;
  const int o3h0 = ty * 8, o3w0 = tx * 8;
  const int wave = t >> 6, lane = t & 63, quad = lane >> 4, l16 = lane & 15;

  int a3off[4];
#pragma unroll
  for (int mf = 0; mf < 4; ++mf) {
    const int px = mf * 16 + l16;
    a3off[mf] = ((quad * 17 + (px >> 3) * 2) * 18 + (px & 7)) * 8;
  }

  floatx4 acc3[4][2];
#pragma unroll
  for (int mf = 0; mf < 4; ++mf) {
    acc3[mf][0] = (floatx4){0.f, 0.f, 0.f, 0.f};
    acc3[mf][1] = (floatx4){0.f, 0.f, 0.f, 0.f};
  }

  const int h0 = o3h0 * 2 - 1, w0 = o3w0 * 2 - 1;
#pragma unroll
  for (int h = 0; h < 2; ++h) {
    if (h) __syncthreads();  // previous half's reads done
    for (int c = t; c < 17 * 17 * 4; c += 256) {
      const int pix = c >> 2, seg = c & 3;
      const int pi = pix / 17, pj = pix % 17;
      const int ih = h0 + pi, iw = w0 + pj;
      uint4 v = make_uint4(0u, 0u, 0u, 0u);
      if ((unsigned)ih < 112u && (unsigned)iw < 112u)
        v = *(const uint4*)(act2 + (((size_t)img * 112 + ih) * 112 + iw) * 64 +
                            h * 32 + seg * 8);
      const int slot = (pj >> 1) + (pj & 1) * 9;  // parity split (stride 2)
      *(uint4*)(&c2p[((seg * 17 + pi) * 18 + slot) * 8]) = v;
    }
    __syncthreads();
#pragma unroll
    for (int tap = 0; tap < 9; ++tap) {
      const int kh = tap / 3, kw = tap % 3;
      const int kg = tap * 8 + h * 4 + quad;
      const short8 b0 = *(const short8*)(
          bp3 + ((size_t)kg * 128 + wave * 32 + l16) * 8);
      const short8 b1 = *(const short8*)(
          bp3 + ((size_t)kg * 128 + wave * 32 + 16 + l16) * 8);
      const int toff = (kh * 18 + (kw >> 1) + (kw & 1) * 9) * 8;
#pragma unroll
      for (int mf = 0; mf < 4; ++mf) {
        const short8 a = *(const short8*)(&c2p[a3off[mf] + toff]);
        acc3[mf][0] = __builtin_amdgcn_mfma_f32_16x16x32_bf16(
            a, b0, acc3[mf][0], 0, 0, 0);
        acc3[mf][1] = __builtin_amdgcn_mfma_f32_16x16x32_bf16(
            a, b1, acc3[mf][1], 0, 0, 0);
      }
    }
  }

  // ---- BN3 + ReLU + pool (waves own disjoint 32-ch slices)
#pragma unroll
  for (int nf = 0; nf < 2; ++nf) {
    const int ch = wave * 32 + nf * 16 + l16;
    const float sc = s3[ch], bs = bb3[ch];
    float s = 0.f;
#pragma unroll
    for (int mf = 0; mf < 4; ++mf)
#pragma unroll
      for (int r = 0; r < 4; ++r)
        s += fmaxf(acc3[mf][nf][r] * sc + bs, 0.f);
    s += __shfl_xor(s, 16);
    s += __shfl_xor(s, 32);
    if (lane < 16) pbuf[ch] = s;
  }
  __syncthreads();
  if (t < 128) atomicAdd(&pooled[(size_t)img * 128 + t], pbuf[t]);
}

// ---------------------------------------------------------------- linear
// pooled holds SUMS over 3136 px; ql holds signs; alpha_l from red.
__global__ void linear_kernel(const float* __restrict__ pooled,
                              const float* __restrict__ ql,
                              const float* __restrict__ bl,
                              const float* __restrict__ red,
                              float* __restrict__ out) {
  const int idx = blockIdx.x * blockDim.x + threadIdx.x;
  if (idx >= 64 * 10) return;
  const int n = idx / 10, o = idx % 10;
  const float* p = pooled + (size_t)n * 128;
  const float* w = ql + (size_t)o * 128;
  float s = 0.f;
#pragma unroll 4
  for (int c = 0; c < 128; ++c) s += p[c] * w[c];
  const float alpha_l = red[14] / fmaxf(red[13], 1.f);
  out[idx] = s * (alpha_l / 3136.f) + bl[o];
}

// ---------------------------------------------------------------- launch
extern "C" void kernel_launch(void* const* d_in, const int* in_sizes, int n_in,
                              void* d_out, int out_size, void* d_ws,
                              size_t ws_size, hipStream_t stream) {
  const float* x  = (const float*)d_in[0];
  const float* w1 = (const float*)d_in[1];
  const float* g1 = (const float*)d_in[2];
  const float* b1 = (const float*)d_in[3];
  const float* m1 = (const float*)d_in[4];
  const float* v1 = (const float*)d_in[5];
  const float* w2 = (const float*)d_in[6];
  const float* g2 = (const float*)d_in[7];
  const float* b2 = (const float*)d_in[8];
  const float* m2 = (const float*)d_in[9];
  const float* v2 = (const float*)d_in[10];
  const float* w3 = (const float*)d_in[11];
  const float* g3 = (const float*)d_in[12];
  const float* b3 = (const float*)d_in[13];
  const float* m3 = (const float*)d_in[14];
  const float* v3 = (const float*)d_in[15];
  const float* wl = (const float*)d_in[16];
  const float* bl = (const float*)d_in[17];
  float* out = (float*)d_out;

  // ---- workspace layout (red/pooled/bp1 contiguous -> one zeroing memset)
  float* Wf = (float*)d_ws;
  float* red = Wf;                        // 16
  float* pooled = red + 16;               // 8192
  float* bp1f = pooled + 8192;            // 512 floats = 1024 shorts (K32xN32)
  float* ql = bp1f + 512;                 // 1280
  float* s1 = ql + 1280;  float* bb1 = s1 + 32;
  float* s2 = bb1 + 32;   float* bb2 = s2 + 64;
  float* s3 = bb2 + 64;   float* bb3 = s3 + 128;
  unsigned short* bp1 = (unsigned short*)bp1f;
  unsigned short* Us = (unsigned short*)(bb3 + 128);
  unsigned short* bp2 = Us;                 // 18432
  unsigned short* bp3 = bp2 + 18432;        // 73728
  unsigned short* act1 = bp3 + 73728;       // 64*12544*32 = 25690112
  unsigned short* act2 = act1 + 25690112;   // 64*12544*64 = 51380224
  // total ~155 MB < ws_size

  // ---- prep: memset + 2 reduction/pack phases + tiny BN fold ----
  hipMemsetAsync(red, 0, (16 + 8192 + 512) * sizeof(float), stream);
  tern_phase1<<<dim3(288, 4), 256, 0, stream>>>(w1, w2, w3, wl, 864, 18432,
                                                73728, 1280, red);
  tern_phase2<<<dim3(288, 4), 256, 0, stream>>>(w1, w2, w3, wl, 864, 18432,
                                                73728, 1280, red, bp1, bp2,
                                                bp3, ql);
  bnfold_all<<<1, 256, 0, stream>>>(g1, b1, m1, v1, g2, b2, m2, v2, g3, b3,
                                    m3, v3, s1, bb1, s2, bb2, s3, bb3, red);

  // ---- network ----
  conv1_mfma<<<dim3(98, 64), 256, 0, stream>>>(x, bp1, s1, bb1, act1);
  conv2_halo<<<dim3(98, 1, 64), 256, 0, stream>>>(act1, bp2, s2, bb2, act2);
  conv3_pool<<<dim3(49, 64), 256, 0, stream>>>(act2, bp3, s3, bb3, pooled);
  linear_kernel<<<3, 256, 0, stream>>>(pooled, ql, bl, red, out);
}